// Round 16
// baseline (467.062 us; speedup 1.0000x reference)
//
#include <hip/hip_runtime.h>

#define HIDDEN 1024
#define FF 2048
#define NEXP 8
#define NTOK 16384
#define NPAIR (2 * NTOK)
#define MAXT 264   // sum_e ceil(cnt[e]/128) <= 256 + 8

typedef short short8 __attribute__((ext_vector_type(8)));
typedef unsigned short ushort4v __attribute__((ext_vector_type(4)));
typedef float f32x4 __attribute__((ext_vector_type(4)));

// fp32 -> bf16 bits, round-to-nearest-even
__device__ __forceinline__ unsigned short f2b(float f) {
  union { float f; unsigned int u; } v; v.f = f;
  unsigned int u = v.u;
  return (unsigned short)((u + 0x7fffu + ((u >> 16) & 1u)) >> 16);
}
__device__ __forceinline__ float b2f(unsigned short b) {
  union { unsigned int u; float f; } v; v.u = ((unsigned int)b) << 16;
  return v.f;
}

// async global->LDS, 16B per lane. LDS dest = wave-uniform base + lane*16.
__device__ __forceinline__ void gload16(const unsigned short* g, unsigned short* l) {
  __builtin_amdgcn_global_load_lds(
      (const __attribute__((address_space(1))) unsigned int*)g,
      (__attribute__((address_space(3))) unsigned int*)l,
      16, 0, 0);
}

// counted vmcnt waits: asm memory clobber (compiler fence) + sched fence (rule 18)
#define PIPE_WAIT(n) do { \
    asm volatile("s_waitcnt vmcnt(" #n ")" ::: "memory"); \
    __builtin_amdgcn_sched_barrier(0); \
  } while (0)
// raw barrier that IS a compiler memory fence, plus sched fence
#define ABAR do { \
    asm volatile("s_barrier" ::: "memory"); \
    __builtin_amdgcn_sched_barrier(0); \
  } while (0)

// ---------------- workspace layout (bytes) ----------------
// w1t and xb (both DEAD after ffn1) adjacent; ypair aliases that 64MB region.
// Keeping out untouched until the final combine keeps the hot set < L3 (R15 win).
#define W2T_OFF 0ull                                                      // [E][HIDDEN][FF] bf16, 32MB
#define W1T_OFF (W2T_OFF + (unsigned long long)NEXP * HIDDEN * FF * 2)    // [E][FF][HIDDEN] bf16, 32MB
#define XB_OFF  (W1T_OFF + (unsigned long long)NEXP * FF * HIDDEN * 2)    // [NTOK][HIDDEN] bf16, 32MB
#define H_OFF   (XB_OFF + (unsigned long long)NTOK * HIDDEN * 2)          // [NPAIR][FF] bf16, 128MB
#define CNT_OFF (H_OFF + (unsigned long long)NPAIR * FF * 2)              // [E] int
#define PLIST_OFF (CNT_OFF + 256ull)                                      // [E][NTOK] int
#define PW_OFF    (PLIST_OFF + (unsigned long long)NEXP * NTOK * 4)       // [NPAIR] float
#define TOPS_OFF  (PW_OFF + (unsigned long long)NPAIR * 4)                // [NTOK] int
#define W0_OFF    (TOPS_OFF + (unsigned long long)NTOK * 4)               // [NTOK] float
#define WQ_OFF    (W0_OFF + (unsigned long long)NTOK * 4)                 // [MAXT] int
#define YP_OFF    W1T_OFF   // [NPAIR][HIDDEN] bf16, 64MB — aliases w1t+xb (dead after ffn1)
#define WS_NEED   (WQ_OFF + 4096ull)

// zero out (atomic-fallback path only). hipMemsetAsync is NOT replay-safe (R10).
__global__ void zero_out_k(float4* __restrict__ out) {
  out[(size_t)blockIdx.x * 256 + threadIdx.x] = float4{0.f, 0.f, 0.f, 0.f};
}

// in: [E][R][C] f32  ->  out: [E][C][R] bf16
__global__ void transpose_cast_k(const float* __restrict__ in,
                                 unsigned short* __restrict__ out,
                                 int R, int C) {
  __shared__ float tile[32][33];
  const size_t eoff = (size_t)blockIdx.z * R * C;
  const float* inp = in + eoff;
  unsigned short* outp = out + eoff;
  const int c = threadIdx.x & 31;
  const int r0 = threadIdx.x >> 5;
  const int gr = blockIdx.y * 32, gc = blockIdx.x * 32;
#pragma unroll
  for (int i = 0; i < 4; i++) {
    int r = r0 + i * 8;
    tile[r][c] = inp[(size_t)(gr + r) * C + gc + c];
  }
  __syncthreads();
#pragma unroll
  for (int i = 0; i < 4; i++) {
    int r = r0 + i * 8;
    outp[(size_t)(gc + r) * R + gr + c] = f2b(tile[c][r]);
  }
}

// one wave per token: logits over 8 experts, top-2, renorm; fused x->bf16 cast.
// Also zeroes cnt (block 0) — runs before scatter via kernel boundary.
__global__ void router_k(const float* __restrict__ x, const float* __restrict__ rw,
                         const float* __restrict__ rb, int* __restrict__ tops,
                         float* __restrict__ w0f, unsigned short* __restrict__ xb,
                         int* __restrict__ cnt) {
  if (blockIdx.x == 0 && threadIdx.x < NEXP) cnt[threadIdx.x] = 0;
  const int wid = threadIdx.x >> 6;
  const int lane = threadIdx.x & 63;
  const int t = blockIdx.x * 4 + wid;
  const float* xr = x + (size_t)t * HIDDEN;
  float acc[8];
#pragma unroll
  for (int e = 0; e < 8; e++) acc[e] = 0.f;
#pragma unroll
  for (int i = 0; i < 16; i++) {
    int hh = lane + 64 * i;
    float xv = xr[hh];
    const float4* rwp = reinterpret_cast<const float4*>(rw + (size_t)hh * 8);
    float4 a = rwp[0], b = rwp[1];
    acc[0] += xv * a.x; acc[1] += xv * a.y; acc[2] += xv * a.z; acc[3] += xv * a.w;
    acc[4] += xv * b.x; acc[5] += xv * b.y; acc[6] += xv * b.z; acc[7] += xv * b.w;
  }
  // fused cast: x row -> xb row (vectorized, L2-hot after the dot loop)
  {
    const float4* xr4 = reinterpret_cast<const float4*>(xr);
    unsigned short* xbr = xb + (size_t)t * HIDDEN;
#pragma unroll
    for (int i = 0; i < 4; i++) {
      float4 f = xr4[lane + 64 * i];
      ushort4v o;
      o[0] = f2b(f.x); o[1] = f2b(f.y); o[2] = f2b(f.z); o[3] = f2b(f.w);
      *reinterpret_cast<ushort4v*>(&xbr[(lane + 64 * i) * 4]) = o;
    }
  }
#pragma unroll
  for (int off = 32; off; off >>= 1) {
#pragma unroll
    for (int e = 0; e < 8; e++) acc[e] += __shfl_xor(acc[e], off);
  }
  if (lane == 0) {
#pragma unroll
    for (int e = 0; e < 8; e++) acc[e] += rb[e];
    int i0 = 0; float m0 = acc[0];
#pragma unroll
    for (int e = 1; e < 8; e++) if (acc[e] > m0) { m0 = acc[e]; i0 = e; }
    int i1 = -1; float m1 = -1e30f;
#pragma unroll
    for (int e = 0; e < 8; e++) if (e != i0 && acc[e] > m1) { m1 = acc[e]; i1 = e; }
    float w0 = 1.f / (1.f + __expf(m1 - m0));
    tops[t] = i0 | (i1 << 4);
    w0f[t] = w0;
  }
}

// block-aggregated scatter: 256 tokens/block, LDS histogram, 8 global atomics/block
__global__ __launch_bounds__(256)
void scatter_k(const int* __restrict__ tops, const float* __restrict__ w0f,
               int* __restrict__ cnt, int* __restrict__ plist, float* __restrict__ pw) {
  __shared__ int lcnt[NEXP];
  __shared__ int lbase[NEXP];
  const int tid = threadIdx.x;
  const int t = blockIdx.x * 256 + tid;
  if (tid < NEXP) lcnt[tid] = 0;
  __syncthreads();
  const int packed = tops[t];
  const int i0 = packed & 15, i1 = packed >> 4;
  const float w0 = w0f[t];
  const int s0 = atomicAdd(&lcnt[i0], 1);
  const int s1 = atomicAdd(&lcnt[i1], 1);
  __syncthreads();
  if (tid < NEXP) lbase[tid] = atomicAdd(&cnt[tid], lcnt[tid]);
  __syncthreads();
  plist[i0 * NTOK + lbase[i0] + s0] = 2 * t;
  plist[i1 * NTOK + lbase[i1] + s1] = 2 * t + 1;
  pw[2 * t] = w0;
  pw[2 * t + 1] = 1.f - w0;
}

// build compact (expert, 128-row m-tile) work list
__global__ void plan_k(const int* __restrict__ cnt, int* __restrict__ workq) {
  if (threadIdx.x == 0) {
    int idx = 0;
    for (int e = 0; e < NEXP; e++) {
      int nt = (cnt[e] + 127) >> 7;
      for (int m = 0; m < nt; m++) workq[idx++] = (e << 16) | m;
    }
    while (idx < MAXT) workq[idx++] = -1;
  }
}

// combine: out[t] = w0 * ypair[2t] + w1 * ypair[2t+1]  (bf16 in, fp32 out)
// Sole writer of out => no zero pass, no atomics, replay-deterministic.
__global__ __launch_bounds__(256)
void combine_k(const unsigned short* __restrict__ ypair, const float* __restrict__ pw,
               float* __restrict__ out) {
  const int t = blockIdx.x * 2 + (threadIdx.x >> 7);
  const int i = (threadIdx.x & 127) * 8;
  const float w0 = pw[2 * t], w1 = pw[2 * t + 1];
  const short8 y0 = *(const short8*)&ypair[(size_t)(2 * t) * HIDDEN + i];
  const short8 y1 = *(const short8*)&ypair[(size_t)(2 * t + 1) * HIDDEN + i];
  float* orow = out + (size_t)t * HIDDEN + i;
#pragma unroll
  for (int j = 0; j < 8; j++)
    orow[j] = w0 * b2f((unsigned short)y0[j]) + w1 * b2f((unsigned short)y1[j]);
}

// Grouped GEMM, 128(m) x 256(n) tile, 8 waves (512 thr), BK=32, 3-deep
// counted-vmcnt pipeline (R8/R11-proven sync skeleton; parameter rescale).
// Unified LDS S[3][384][32]: rows 0-127 = A-tile, 128-383 = B-tile (72 KB)
// => 2 blocks/CU = 16 waves/CU (50% occ, up from 12) and 25% less staged
// bytes per output element.
//
// vmcnt ledger (per wave, 3 gload16 issues per tile — 48 of 384 rows each):
//   prologue: stage T0,T1,T2                 -> 9 outstanding
//   iter t:   WAIT(t<NT-2 ? 6 : t==NT-2 ? 3 : 0)  -> T_t resident
//             ABAR; 8 ds_read + 16 MFMA; ABAR; stage T_{t+3} into freed buf
// Every issue covers 16 aligned rows (w8*48+j*16), so no issue straddles the
// A/B boundary at row 128; LDS dest stays wave-uniform + lane*16.
// 4-slot both-sides swizzle as R11 (global slot (l&3)^((l>>2)&3), read col
// (fg^(fr&3))*16B).
// PHASE 1: h[pair] = relu(xb[token] @ w1t[e]^T + b1[e])  (K=1024,N=2048)
// PHASE 2: ypair[pair] = h[pair] @ w2t[e]^T + b2[e]      (K=2048,N=1024)  [YP=1]
//          or atomic out += pw * (...)                   [YP=0 fallback]
template <int PHASE, int YP>
__global__ __launch_bounds__(512, 4)
void ffn_k(const unsigned short* __restrict__ xb, const unsigned short* __restrict__ wT,
           const float* __restrict__ bias, const unsigned short* __restrict__ hin,
           unsigned short* __restrict__ hout, float* __restrict__ out,
           const int* __restrict__ cnt, const int* __restrict__ plist,
           const float* __restrict__ pw, const int* __restrict__ workq) {
  constexpr int K = (PHASE == 1) ? HIDDEN : FF;
  constexpr int N = (PHASE == 1) ? FF : HIDDEN;
  constexpr int NT = K / 32;
  constexpr int NTN = N / 256;
  constexpr int NWG = MAXT * NTN;   // 2112 / 1056, both % 8 == 0

  // bijective XCD swizzle (m204)
  constexpr int q8 = NWG / 8;
  const int bid = blockIdx.x;
  const int wgid = (bid & 7) * q8 + (bid >> 3);
  const int mt = wgid / NTN;
  const int n0g = (wgid % NTN) * 256;

  const int w = workq[mt];
  if (w < 0) return;
  const int e = w >> 16;
  const int m0g = (w & 0xffff) * 128;
  const int mcnt = cnt[e];
  const int mrem = mcnt - m0g;

  // unified triple-buffered LDS: rows 0-127 A, 128-383 B. 3 x 24 KB = 72 KB.
  __shared__ alignas(16) unsigned short S[3][384][32];
  __shared__ int rowpair[128];

  const int tid = threadIdx.x;
  if (tid < 128) rowpair[tid] = (tid < mrem) ? plist[e * NTOK + m0g + tid] : -1;
  __syncthreads();

  const int w8 = tid >> 6;   // wave 0..7
  const int lane = tid & 63;

  // staging: wave w8 covers rows [w8*48, w8*48+48) via 3 issues of 16 rows.
  // lane l -> row +(l>>2), LDS slot (l&3); GLOBAL slot pre-swizzled.
  const int sslot = (lane & 3) ^ ((lane >> 2) & 3);
  const int rsub = lane >> 2;
  const unsigned short* wTe = wT + (size_t)e * N * K;

  const unsigned short* gS[3];
  int ldsRow[3];
#pragma unroll
  for (int j = 0; j < 3; j++) {
    const int gr = w8 * 48 + j * 16;      // issue base row (multiple of 16)
    ldsRow[j] = gr;
    const int r = gr + rsub;              // per-lane row
    if (gr < 128) {                       // A rows (uniform per issue)
      int p = rowpair[r];
      if (p < 0) p = 0;                   // dummy valid row; never written back
      const unsigned short* abase;
      if constexpr (PHASE == 1) abase = xb + (size_t)(p >> 1) * HIDDEN;
      else                      abase = hin + (size_t)p * FF;
      gS[j] = abase + sslot * 8;
    } else {                              // B rows
      gS[j] = wTe + (size_t)(n0g + (r - 128)) * K + sslot * 8;
    }
  }

  // wave sub-tile: 64(m) x 64(n); 2x4 wave grid
  const int wr = (w8 >> 2) * 64;          // A row base (0 or 64)
  const int wc = (w8 & 3) * 64;           // B row base within tile (0..192)
  const int fr = lane & 15;
  const int fg = lane >> 4;
  const int fsw = fr & 3;                 // read-side swizzle term

  f32x4 acc[4][4];
#pragma unroll
  for (int i = 0; i < 4; i++)
#pragma unroll
    for (int j = 0; j < 4; j++) acc[i][j] = f32x4{0.f, 0.f, 0.f, 0.f};

  // ---- prologue: tiles 0,1,2 -> bufs 0,1,2 (9 issues in flight per wave) ----
#pragma unroll
  for (int b = 0; b < 3; b++)
#pragma unroll
    for (int j = 0; j < 3; j++)
      gload16(gS[j] + b * 32, &S[b][ldsRow[j]][0]);

  int cur = 0;
  for (int t = 0; t < NT; ++t) {
    if (t < NT - 2)       PIPE_WAIT(6);  // tile t done; t+1,t+2 stay in flight
    else if (t == NT - 2) PIPE_WAIT(3);
    else                  PIPE_WAIT(0);
    ABAR;  // all waves' tile-t loads now visible

    short8 af[4], bf[4];
#pragma unroll
    for (int mi = 0; mi < 4; mi++)
      af[mi] = *(const short8*)&S[cur][wr + mi * 16 + fr][(fg ^ fsw) * 8];
#pragma unroll
    for (int ni = 0; ni < 4; ni++)
      bf[ni] = *(const short8*)&S[cur][128 + wc + ni * 16 + fr][(fg ^ fsw) * 8];
#pragma unroll
    for (int mi = 0; mi < 4; mi++)
#pragma unroll
      for (int ni = 0; ni < 4; ni++)
        acc[mi][ni] = __builtin_amdgcn_mfma_f32_16x16x32_bf16(af[mi], bf[ni], acc[mi][ni], 0, 0, 0);

    ABAR;  // all waves done READING buf[cur]; safe to overwrite

    if (t + 3 < NT) {
      const int kt = (t + 3) * 32;
#pragma unroll
      for (int j = 0; j < 3; j++)
        gload16(gS[j] + kt, &S[cur][ldsRow[j]][0]);
    }
    cur = (cur == 2) ? 0 : cur + 1;
  }

  // ---- epilogue ----
  float bv[4];
#pragma unroll
  for (int ni = 0; ni < 4; ni++) bv[ni] = bias[(size_t)e * N + n0g + wc + ni * 16 + fr];

#pragma unroll
  for (int mi = 0; mi < 4; mi++) {
#pragma unroll
    for (int r = 0; r < 4; r++) {
      int m = wr + mi * 16 + fg * 4 + r;
      if (m >= mrem) continue;
      int p = rowpair[m];
      if constexpr (PHASE == 1) {
        unsigned short* hr = hout + (size_t)p * FF + n0g;
#pragma unroll
        for (int ni = 0; ni < 4; ni++) {
          float v = acc[mi][ni][r] + bv[ni];
          hr[wc + ni * 16 + fr] = f2b(fmaxf(v, 0.f));
        }
      } else if constexpr (YP == 1) {
        unsigned short* yr = hout + (size_t)p * HIDDEN + n0g;
#pragma unroll
        for (int ni = 0; ni < 4; ni++) {
          float v = acc[mi][ni][r] + bv[ni];
          yr[wc + ni * 16 + fr] = f2b(v);
        }
      } else {
        float wgt = pw[p];
        float* orow = out + (size_t)(p >> 1) * HIDDEN + n0g;
#pragma unroll
        for (int ni = 0; ni < 4; ni++) {
          float v = (acc[mi][ni][r] + bv[ni]) * wgt;
          atomicAdd(&orow[wc + ni * 16 + fr], v);
        }
      }
    }
  }
}

extern "C" void kernel_launch(void* const* d_in, const int* in_sizes, int n_in,
                              void* d_out, int out_size, void* d_ws, size_t ws_size,
                              hipStream_t stream) {
  const float* x  = (const float*)d_in[0];
  const float* rw = (const float*)d_in[1];
  const float* rb = (const float*)d_in[2];
  const float* w1 = (const float*)d_in[3];
  const float* b1 = (const float*)d_in[4];
  const float* w2 = (const float*)d_in[5];
  const float* b2 = (const float*)d_in[6];
  float* out = (float*)d_out;
  char* ws = (char*)d_ws;

  unsigned short* w2t = (unsigned short*)(ws + W2T_OFF);
  unsigned short* w1t = (unsigned short*)(ws + W1T_OFF);
  unsigned short* xb  = (unsigned short*)(ws + XB_OFF);
  unsigned short* h   = (unsigned short*)(ws + H_OFF);
  int* cnt   = (int*)(ws + CNT_OFF);
  int* plist = (int*)(ws + PLIST_OFF);
  float* pwt = (float*)(ws + PW_OFF);
  int* tops  = (int*)(ws + TOPS_OFF);
  float* w0f = (float*)(ws + W0_OFF);
  int* workq = (int*)(ws + WQ_OFF);
  unsigned short* ypair = (unsigned short*)(ws + YP_OFF);  // aliases w1t+xb

  const bool use_yp = (ws_size >= WS_NEED);

  if (!use_yp)
    hipLaunchKernelGGL(zero_out_k, dim3(16384), dim3(256), 0, stream, (float4*)out);
  hipLaunchKernelGGL(transpose_cast_k, dim3(FF / 32, HIDDEN / 32, NEXP), dim3(256), 0, stream,
                     w1, w1t, HIDDEN, FF);
  hipLaunchKernelGGL(transpose_cast_k, dim3(HIDDEN / 32, FF / 32, NEXP), dim3(256), 0, stream,
                     w2, w2t, FF, HIDDEN);
  hipLaunchKernelGGL(router_k, dim3(NTOK / 4), dim3(256), 0, stream, x, rw, rb, tops, w0f, xb, cnt);
  hipLaunchKernelGGL(scatter_k, dim3(NTOK / 256), dim3(256), 0, stream, tops, w0f, cnt, plist, pwt);
  hipLaunchKernelGGL(plan_k, dim3(1), dim3(64), 0, stream, cnt, workq);
  hipLaunchKernelGGL((ffn_k<1, 0>), dim3(MAXT * (FF / 256)), dim3(512), 0, stream,
                     xb, w1t, b1, (const unsigned short*)nullptr, h, (float*)nullptr,
                     cnt, plist, pwt, workq);
  if (use_yp) {
    hipLaunchKernelGGL((ffn_k<2, 1>), dim3(MAXT * (HIDDEN / 256)), dim3(512), 0, stream,
                       xb, w2t, b2, h, ypair, (float*)nullptr,
                       cnt, plist, pwt, workq);
    hipLaunchKernelGGL(combine_k, dim3(NTOK / 2), dim3(256), 0, stream, ypair, pwt, out);
  } else {
    hipLaunchKernelGGL((ffn_k<2, 0>), dim3(MAXT * (HIDDEN / 256)), dim3(512), 0, stream,
                       xb, w2t, b2, h, (unsigned short*)nullptr, out,
                       cnt, plist, pwt, workq);
  }
}